// Round 7
// baseline (755.875 us; speedup 1.0000x reference)
//
#include <hip/hip_runtime.h>
#include <stdint.h>

#define T_TOK 2048
#define HDIM 1024
#define NEXP 8
#define IDIM 3584
#define MAXTILE 40
#define WELEM (NEXP * IDIM * HDIM)   // 29,360,128 elems per weight tensor

// ws layout (bytes)
#define WS_CNT   0
#define WS_BASE  64
#define WS_TE    128
#define WS_TM    384
#define WS_NT    640
#define WS_TOK   704
#define WS_GW    (WS_TOK + NEXP * T_TOK * 4)
#define WS_XB    (WS_GW + NEXP * T_TOK * 4)
#define WS_G     (WS_XB + T_TOK * HDIM * 2)
#define WS_WB    (WS_G + (size_t)4096 * IDIM * 2)   // bf16 weights: 3 x 2*WELEM bytes

typedef __attribute__((ext_vector_type(8))) short bf16x8;
typedef __attribute__((ext_vector_type(16))) float f32x16;

__device__ __forceinline__ unsigned short f2bf(float f) {
    union { float f; unsigned int u; } a; a.f = f;
    unsigned int u = a.u;
    return (unsigned short)((u + 0x7fffu + ((u >> 16) & 1u)) >> 16);
}

// packed fp32->bf16 RNE, 2 elems / instr
__device__ __forceinline__ unsigned int cvt_pk_bf16(float lo, float hi) {
    unsigned int r;
    asm("v_cvt_pk_bf16_f32 %0, %1, %2" : "=v"(r) : "v"(lo), "v"(hi));
    return r;
}

__device__ __forceinline__ uint4 pack8(const float4 a, const float4 b) {
    uint4 r;
    r.x = cvt_pk_bf16(a.x, a.y);
    r.y = cvt_pk_bf16(a.z, a.w);
    r.z = cvt_pk_bf16(b.x, b.y);
    r.w = cvt_pk_bf16(b.z, b.w);
    return r;
}

__global__ __launch_bounds__(256) void xcvt_kernel(
    const float* __restrict__ x, unsigned short* __restrict__ xb)
{
    int i = (blockIdx.x * 256 + threadIdx.x) * 8;
    float4 a = *(const float4*)(x + i);
    float4 b = *(const float4*)(x + i + 4);
    *(uint4*)(xb + i) = pack8(a, b);
}

// stream-convert the three weight tensors to bf16 (layout-preserving)
__global__ __launch_bounds__(256) void wcvt_kernel(
    const float* __restrict__ w1, const float* __restrict__ w2,
    const float* __restrict__ w3,
    unsigned short* __restrict__ b1, unsigned short* __restrict__ b2,
    unsigned short* __restrict__ b3)
{
    const float* src; unsigned short* dst;
    if (blockIdx.y == 0)      { src = w1; dst = b1; }
    else if (blockIdx.y == 1) { src = w2; dst = b2; }
    else                      { src = w3; dst = b3; }
    size_t t = (size_t)blockIdx.x * 256 + threadIdx.x;   // 0..524287
#pragma unroll
    for (int it = 0; it < 7; ++it) {
        size_t i = (t + (size_t)it * 524288) * 8;        // WELEM = 524288*7*8
        float4 a = *(const float4*)(src + i);
        float4 b = *(const float4*)(src + i + 4);
        *(uint4*)(dst + i) = pack8(a, b);
    }
}

__global__ __launch_bounds__(256) void router_kernel(
    const float* __restrict__ x, const float* __restrict__ gate_w,
    int* __restrict__ cnt, int* __restrict__ tok, float* __restrict__ gw)
{
    int t = blockIdx.x * 4 + (threadIdx.x >> 6);
    int lane = threadIdx.x & 63;
    if (t >= T_TOK) return;
    const float* xr = x + (size_t)t * HDIM;
    float part[NEXP];
#pragma unroll
    for (int e = 0; e < NEXP; e++) part[e] = 0.f;
    for (int h = lane; h < HDIM; h += 64) {
        float xv = xr[h];
#pragma unroll
        for (int e = 0; e < NEXP; e++) part[e] += xv * gate_w[e * HDIM + h];
    }
#pragma unroll
    for (int e = 0; e < NEXP; e++) {
        float v = part[e];
#pragma unroll
        for (int o = 32; o > 0; o >>= 1) v += __shfl_xor(v, o);
        part[e] = v;
    }
    if (lane == 0) {
        int i0 = 0; float v0 = part[0];
#pragma unroll
        for (int e = 1; e < NEXP; e++) if (part[e] > v0) { v0 = part[e]; i0 = e; }
        int i1 = -1; float v1 = -3.4e38f;
#pragma unroll
        for (int e = 0; e < NEXP; e++) if (e != i0 && part[e] > v1) { v1 = part[e]; i1 = e; }
        float d = __expf(v1 - v0);
        float w1v = d / (1.f + d);
        float w0v = 1.f - w1v;
        int p0 = atomicAdd(&cnt[i0], 1);
        tok[i0 * T_TOK + p0] = t; gw[i0 * T_TOK + p0] = w0v;
        int p1 = atomicAdd(&cnt[i1], 1);
        tok[i1 * T_TOK + p1] = t; gw[i1 * T_TOK + p1] = w1v;
    }
}

__global__ void scan_kernel(const int* __restrict__ cnt, int* __restrict__ base,
                            int* __restrict__ tileE, int* __restrict__ tileM,
                            int* __restrict__ ntot)
{
    if (threadIdx.x == 0) {
        int s = 0, nt = 0;
        for (int e = 0; e < NEXP; e++) {
            base[e] = s; s += cnt[e];
            for (int m0 = 0; m0 < cnt[e]; m0 += 128) {
                tileE[nt] = e; tileM[nt] = m0; nt++;
            }
        }
        *ntot = nt;
    }
}

// ffn1: g = silu(x@w1^T) * (x@w3^T). Tile 128 tok x 128 i, BK=64, 256 thr,
// 2-phase reg prefetch. WBF16: weights pre-converted to bf16 (half bytes).
template<bool WBF16>
__global__ __launch_bounds__(256, 2) void ffn1_mfma(
    const unsigned short* __restrict__ xb,
    const void* __restrict__ w1p,
    const void* __restrict__ w3p,
    const int* __restrict__ cnt, const int* __restrict__ base,
    const int* __restrict__ tok,
    const int* __restrict__ tileE, const int* __restrict__ tileM,
    const int* __restrict__ ntot,
    unsigned short* __restrict__ g)
{
    // XCD panel-affinity swizzle: 1120 blocks, chunked per XCD, panel-major
    const int wg = blockIdx.x;
    const int lid = (wg & 7) * (1120 >> 3) + (wg >> 3);
    const int bx = lid / MAXTILE;          // i-panel 0..27
    const int ti = lid % MAXTILE;
    if (ti >= *ntot) return;
    const int e = tileE[ti];
    const int m0 = tileM[ti];
    const int cntE = cnt[e];
    const int i0 = bx * 128;
    const int tid = threadIdx.x;
    const int lane = tid & 63;
    const int wid = tid >> 6;

    __shared__ __align__(16) unsigned char lds[49152]; // xs 16K | w1s 16K | w3s 16K
    __shared__ int toks_s[128];
    if (tid < 128) toks_s[tid] = tok[e * T_TOK + min(m0 + tid, cntE - 1)];
    __syncthreads();

    const int rw = tid >> 3;              // staging row 0..31
    const int kc = tid & 7;               // 16B chunk in row
    const unsigned int dcol = ((unsigned)(kc * 16)) ^ ((unsigned)((rw & 7) << 4));

    int tk[4];
#pragma unroll
    for (int j = 0; j < 4; j++) tk[j] = toks_s[rw + 32 * j];

    const unsigned int XS = 0, W1S = 16384, W3S = 32768;

    f32x16 acc1[2][2], acc3[2][2];
#pragma unroll
    for (int a = 0; a < 2; a++)
#pragma unroll
        for (int b = 0; b < 2; b++)
#pragma unroll
            for (int r = 0; r < 16; r++) { acc1[a][b][r] = 0.f; acc3[a][b][r] = 0.f; }

    const int wr = wid >> 1;              // token half (0/1)
    const int wc = wid & 1;               // i half (0/1)
    const unsigned int lrow = (unsigned)(lane & 31);
    const unsigned int lswz = (lrow & 7) << 4;
    const unsigned int hi16 = (unsigned)((lane >> 5) * 16);
    const unsigned int aBase  = XS  + (wr * 64 + lrow) * 128;
    const unsigned int b1Base = W1S + (wc * 64 + lrow) * 128;
    const unsigned int b3Base = W3S + (wc * 64 + lrow) * 128;

    // staging registers
    uint4 xv[4];
    uint4 wp1[4], wp3[4];                 // WBF16 path
    float4 wva[4][2], wvb[4][2];          // fp32 fallback path

    const unsigned short* w1b; const unsigned short* w3b;
    const float* w1f; const float* w3f;
    if constexpr (WBF16) {
        w1b = (const unsigned short*)w1p + ((size_t)e * IDIM + i0) * HDIM;
        w3b = (const unsigned short*)w3p + ((size_t)e * IDIM + i0) * HDIM;
    } else {
        w1f = (const float*)w1p + ((size_t)e * IDIM + i0) * HDIM;
        w3f = (const float*)w3p + ((size_t)e * IDIM + i0) * HDIM;
    }

    // prologue: load k0 = 0
#pragma unroll
    for (int j = 0; j < 4; j++)
        xv[j] = *(const uint4*)(xb + (size_t)tk[j] * HDIM + kc * 8);
    if constexpr (WBF16) {
#pragma unroll
        for (int j = 0; j < 4; j++) {
            wp1[j] = *(const uint4*)(w1b + (size_t)(rw + 32 * j) * HDIM + kc * 8);
            wp3[j] = *(const uint4*)(w3b + (size_t)(rw + 32 * j) * HDIM + kc * 8);
        }
    } else {
#pragma unroll
        for (int j = 0; j < 4; j++) {
            const float* s1 = w1f + (size_t)(rw + 32 * j) * HDIM + kc * 8;
            wva[j][0] = *(const float4*)s1;
            wva[j][1] = *(const float4*)(s1 + 4);
            const float* s3 = w3f + (size_t)(rw + 32 * j) * HDIM + kc * 8;
            wvb[j][0] = *(const float4*)s3;
            wvb[j][1] = *(const float4*)(s3 + 4);
        }
    }

    for (int k0 = 0; k0 < HDIM; k0 += 64) {
        __syncthreads();   // previous iter's LDS reads complete
#pragma unroll
        for (int j = 0; j < 4; j++)
            *(uint4*)(lds + XS + (rw + 32 * j) * 128 + dcol) = xv[j];
        if constexpr (WBF16) {
#pragma unroll
            for (int j = 0; j < 4; j++) {
                *(uint4*)(lds + W1S + (rw + 32 * j) * 128 + dcol) = wp1[j];
                *(uint4*)(lds + W3S + (rw + 32 * j) * 128 + dcol) = wp3[j];
            }
        } else {
#pragma unroll
            for (int j = 0; j < 4; j++) {
                *(uint4*)(lds + W1S + (rw + 32 * j) * 128 + dcol) = pack8(wva[j][0], wva[j][1]);
                *(uint4*)(lds + W3S + (rw + 32 * j) * 128 + dcol) = pack8(wvb[j][0], wvb[j][1]);
            }
        }

        // issue NEXT iteration's global loads before the barrier
        if (k0 + 64 < HDIM) {
            const int kn = k0 + 64;
#pragma unroll
            for (int j = 0; j < 4; j++)
                xv[j] = *(const uint4*)(xb + (size_t)tk[j] * HDIM + kn + kc * 8);
            if constexpr (WBF16) {
#pragma unroll
                for (int j = 0; j < 4; j++) {
                    wp1[j] = *(const uint4*)(w1b + (size_t)(rw + 32 * j) * HDIM + kn + kc * 8);
                    wp3[j] = *(const uint4*)(w3b + (size_t)(rw + 32 * j) * HDIM + kn + kc * 8);
                }
            } else {
#pragma unroll
                for (int j = 0; j < 4; j++) {
                    const float* s1 = w1f + (size_t)(rw + 32 * j) * HDIM + kn + kc * 8;
                    wva[j][0] = *(const float4*)s1;
                    wva[j][1] = *(const float4*)(s1 + 4);
                    const float* s3 = w3f + (size_t)(rw + 32 * j) * HDIM + kn + kc * 8;
                    wvb[j][0] = *(const float4*)s3;
                    wvb[j][1] = *(const float4*)(s3 + 4);
                }
            }
        }
        __syncthreads();   // LDS writes visible

#pragma unroll
        for (int s = 0; s < 4; s++) {
            const unsigned int off = ((unsigned)(s * 32) + hi16) ^ lswz;
            bf16x8 a0 = *(const bf16x8*)(lds + aBase + off);
            bf16x8 a1 = *(const bf16x8*)(lds + aBase + 32 * 128 + off);
            bf16x8 p0 = *(const bf16x8*)(lds + b1Base + off);
            bf16x8 p1 = *(const bf16x8*)(lds + b1Base + 32 * 128 + off);
            bf16x8 q0 = *(const bf16x8*)(lds + b3Base + off);
            bf16x8 q1 = *(const bf16x8*)(lds + b3Base + 32 * 128 + off);
            acc1[0][0] = __builtin_amdgcn_mfma_f32_32x32x16_bf16(a0, p0, acc1[0][0], 0, 0, 0);
            acc1[0][1] = __builtin_amdgcn_mfma_f32_32x32x16_bf16(a0, p1, acc1[0][1], 0, 0, 0);
            acc1[1][0] = __builtin_amdgcn_mfma_f32_32x32x16_bf16(a1, p0, acc1[1][0], 0, 0, 0);
            acc1[1][1] = __builtin_amdgcn_mfma_f32_32x32x16_bf16(a1, p1, acc1[1][1], 0, 0, 0);
            acc3[0][0] = __builtin_amdgcn_mfma_f32_32x32x16_bf16(a0, q0, acc3[0][0], 0, 0, 0);
            acc3[0][1] = __builtin_amdgcn_mfma_f32_32x32x16_bf16(a0, q1, acc3[0][1], 0, 0, 0);
            acc3[1][0] = __builtin_amdgcn_mfma_f32_32x32x16_bf16(a1, q0, acc3[1][0], 0, 0, 0);
            acc3[1][1] = __builtin_amdgcn_mfma_f32_32x32x16_bf16(a1, q1, acc3[1][1], 0, 0, 0);
        }
    }

    const int pbase = base[e] + m0;
    const int rbase = 4 * (lane >> 5);
#pragma unroll
    for (int ma = 0; ma < 2; ma++) {
#pragma unroll
        for (int r = 0; r < 16; r++) {
            int row = (r & 3) + 8 * (r >> 2) + rbase;
            int m = wr * 64 + ma * 32 + row;
            if (m0 + m < cntE) {
                unsigned short* grow = g + (size_t)(pbase + m) * IDIM + i0 + wc * 64 + lrow;
#pragma unroll
                for (int nb = 0; nb < 2; nb++) {
                    float h1 = acc1[ma][nb][r], h3 = acc3[ma][nb][r];
                    float v = (h1 / (1.f + __expf(-h1))) * h3;
                    grow[nb * 32] = f2bf(v);
                }
            }
        }
    }
}

// ffn2: out[t,h] += gate * (g @ w2^T). Tile 128 pairs x 128 h, split-K x4.
template<bool WBF16>
__global__ __launch_bounds__(256, 2) void ffn2_mfma(
    const unsigned short* __restrict__ g,
    const void* __restrict__ w2p,
    const int* __restrict__ cnt, const int* __restrict__ base,
    const int* __restrict__ tok, const float* __restrict__ gw,
    const int* __restrict__ tileE, const int* __restrict__ tileM,
    const int* __restrict__ ntot,
    float* __restrict__ out)
{
    const int wg = blockIdx.x;
    const int lid = (wg & 7) * (1280 >> 3) + (wg >> 3);
    const int pane = lid / MAXTILE;        // 0..31
    const int ti = lid % MAXTILE;
    if (ti >= *ntot) return;
    const int e = tileE[ti];
    const int m0 = tileM[ti];
    const int cntE = cnt[e];
    const int ks = pane >> 3;
    const int h0 = (pane & 7) * 128;
    const int tid = threadIdx.x;
    const int lane = tid & 63;
    const int wid = tid >> 6;

    __shared__ __align__(16) unsigned char lds[32768]; // gs 16K | w2s 16K
    __shared__ int toks_s[128];
    __shared__ float gws_s[128];
    if (tid < 128) {
        int idx = e * T_TOK + min(m0 + tid, cntE - 1);
        toks_s[tid] = tok[idx];
        gws_s[tid] = gw[idx];
    }
    __syncthreads();

    const int rw = tid >> 3;
    const int kc = tid & 7;
    const unsigned int dcol = ((unsigned)(kc * 16)) ^ ((unsigned)((rw & 7) << 4));

    size_t gp[4];
    const int be = base[e];
#pragma unroll
    for (int j = 0; j < 4; j++)
        gp[j] = (size_t)(be + min(m0 + rw + 32 * j, cntE - 1)) * IDIM;

    const unsigned short* w2b; const float* w2f;
    if constexpr (WBF16) w2b = (const unsigned short*)w2p + ((size_t)e * HDIM + h0) * IDIM;
    else                 w2f = (const float*)w2p + ((size_t)e * HDIM + h0) * IDIM;

    const unsigned int GS = 0, W2S = 16384;

    f32x16 acc[2][2];
#pragma unroll
    for (int a = 0; a < 2; a++)
#pragma unroll
        for (int b = 0; b < 2; b++)
#pragma unroll
            for (int r = 0; r < 16; r++) acc[a][b][r] = 0.f;

    const int wr = wid >> 1;
    const int wc = wid & 1;
    const unsigned int lrow = (unsigned)(lane & 31);
    const unsigned int lswz = (lrow & 7) << 4;
    const unsigned int hi16 = (unsigned)((lane >> 5) * 16);
    const unsigned int aBase = GS  + (wr * 64 + lrow) * 128;
    const unsigned int bBase = W2S + (wc * 64 + lrow) * 128;

    const int kbeg = ks * (IDIM / 4);
    const int kend = kbeg + (IDIM / 4);

    uint4 gv[4], wp2[4]; float4 wv[4][2];
#pragma unroll
    for (int j = 0; j < 4; j++)
        gv[j] = *(const uint4*)(g + gp[j] + kbeg + kc * 8);
    if constexpr (WBF16) {
#pragma unroll
        for (int j = 0; j < 4; j++)
            wp2[j] = *(const uint4*)(w2b + (size_t)(rw + 32 * j) * IDIM + kbeg + kc * 8);
    } else {
#pragma unroll
        for (int j = 0; j < 4; j++) {
            const float* s = w2f + (size_t)(rw + 32 * j) * IDIM + kbeg + kc * 8;
            wv[j][0] = *(const float4*)s;
            wv[j][1] = *(const float4*)(s + 4);
        }
    }

    for (int k0 = kbeg; k0 < kend; k0 += 64) {
        __syncthreads();
#pragma unroll
        for (int j = 0; j < 4; j++)
            *(uint4*)(lds + GS + (rw + 32 * j) * 128 + dcol) = gv[j];
        if constexpr (WBF16) {
#pragma unroll
            for (int j = 0; j < 4; j++)
                *(uint4*)(lds + W2S + (rw + 32 * j) * 128 + dcol) = wp2[j];
        } else {
#pragma unroll
            for (int j = 0; j < 4; j++)
                *(uint4*)(lds + W2S + (rw + 32 * j) * 128 + dcol) = pack8(wv[j][0], wv[j][1]);
        }

        if (k0 + 64 < kend) {
            const int kn = k0 + 64;
#pragma unroll
            for (int j = 0; j < 4; j++)
                gv[j] = *(const uint4*)(g + gp[j] + kn + kc * 8);
            if constexpr (WBF16) {
#pragma unroll
                for (int j = 0; j < 4; j++)
                    wp2[j] = *(const uint4*)(w2b + (size_t)(rw + 32 * j) * IDIM + kn + kc * 8);
            } else {
#pragma unroll
                for (int j = 0; j < 4; j++) {
                    const float* s = w2f + (size_t)(rw + 32 * j) * IDIM + kn + kc * 8;
                    wv[j][0] = *(const float4*)s;
                    wv[j][1] = *(const float4*)(s + 4);
                }
            }
        }
        __syncthreads();

#pragma unroll
        for (int s = 0; s < 4; s++) {
            const unsigned int off = ((unsigned)(s * 32) + hi16) ^ lswz;
            bf16x8 a0 = *(const bf16x8*)(lds + aBase + off);
            bf16x8 a1 = *(const bf16x8*)(lds + aBase + 32 * 128 + off);
            bf16x8 b0 = *(const bf16x8*)(lds + bBase + off);
            bf16x8 b1 = *(const bf16x8*)(lds + bBase + 32 * 128 + off);
            acc[0][0] = __builtin_amdgcn_mfma_f32_32x32x16_bf16(a0, b0, acc[0][0], 0, 0, 0);
            acc[0][1] = __builtin_amdgcn_mfma_f32_32x32x16_bf16(a0, b1, acc[0][1], 0, 0, 0);
            acc[1][0] = __builtin_amdgcn_mfma_f32_32x32x16_bf16(a1, b0, acc[1][0], 0, 0, 0);
            acc[1][1] = __builtin_amdgcn_mfma_f32_32x32x16_bf16(a1, b1, acc[1][1], 0, 0, 0);
        }
    }

    const int rbase = 4 * (lane >> 5);
#pragma unroll
    for (int ma = 0; ma < 2; ma++) {
#pragma unroll
        for (int r = 0; r < 16; r++) {
            int row = (r & 3) + 8 * (r >> 2) + rbase;
            int m = wr * 64 + ma * 32 + row;
            if (m0 + m < cntE) {
                int t = toks_s[m];
                float wgt = gws_s[m];
                float* orow = out + (size_t)t * HDIM + h0 + wc * 64 + lrow;
                atomicAdd(&orow[0],  wgt * acc[ma][0][r]);
                atomicAdd(&orow[32], wgt * acc[ma][1][r]);
            }
        }
    }
}

extern "C" void kernel_launch(void* const* d_in, const int* in_sizes, int n_in,
                              void* d_out, int out_size, void* d_ws, size_t ws_size,
                              hipStream_t stream) {
    const float* x      = (const float*)d_in[0];
    const float* gate_w = (const float*)d_in[1];
    const float* w1     = (const float*)d_in[2];
    const float* w2     = (const float*)d_in[3];
    const float* w3     = (const float*)d_in[4];
    float* out = (float*)d_out;
    char* ws = (char*)d_ws;
    int* cnt   = (int*)(ws + WS_CNT);
    int* base  = (int*)(ws + WS_BASE);
    int* tileE = (int*)(ws + WS_TE);
    int* tileM = (int*)(ws + WS_TM);
    int* ntot  = (int*)(ws + WS_NT);
    int* tok   = (int*)(ws + WS_TOK);
    float* gw  = (float*)(ws + WS_GW);
    unsigned short* xb = (unsigned short*)(ws + WS_XB);
    unsigned short* g  = (unsigned short*)(ws + WS_G);
    unsigned short* wb1 = (unsigned short*)(ws + WS_WB);
    unsigned short* wb3 = wb1 + (size_t)WELEM;
    unsigned short* wb2 = wb3 + (size_t)WELEM;

    const bool use_bf16w = ws_size >= (size_t)WS_WB + 3ull * (size_t)WELEM * 2ull;

    hipMemsetAsync(cnt, 0, 64, stream);
    hipMemsetAsync(d_out, 0, (size_t)out_size * sizeof(float), stream);

    xcvt_kernel<<<T_TOK * HDIM / (256 * 8), 256, 0, stream>>>(x, xb);
    router_kernel<<<T_TOK / 4, 256, 0, stream>>>(x, gate_w, cnt, tok, gw);
    scan_kernel<<<1, 64, 0, stream>>>(cnt, base, tileE, tileM, ntot);

    if (use_bf16w) {
        wcvt_kernel<<<dim3(2048, 3), 256, 0, stream>>>(w1, w2, w3, wb1, wb2, wb3);
        ffn1_mfma<true><<<28 * MAXTILE, 256, 0, stream>>>(xb, wb1, wb3, cnt, base, tok, tileE, tileM, ntot, g);
        ffn2_mfma<true><<<32 * MAXTILE, 256, 0, stream>>>(g, wb2, cnt, base, tok, gw, tileE, tileM, ntot, out);
    } else {
        ffn1_mfma<false><<<28 * MAXTILE, 256, 0, stream>>>(xb, w1, w3, cnt, base, tok, tileE, tileM, ntot, g);
        ffn2_mfma<false><<<32 * MAXTILE, 256, 0, stream>>>(g, w2, cnt, base, tok, gw, tileE, tileM, ntot, out);
    }
}

// Round 8
// 333.948 us; speedup vs baseline: 2.2634x; 2.2634x over previous
//
#include <hip/hip_runtime.h>
#include <stdint.h>

#define T_TOK 2048
#define HDIM 1024
#define NEXP 8
#define IDIM 3584
#define MAXTILE 40

// ws layout (bytes)
#define WS_CNT   0
#define WS_BASE  64
#define WS_TE    128
#define WS_TM    384
#define WS_NT    640
#define WS_TOK   704
#define WS_GW    (WS_TOK + NEXP * T_TOK * 4)
#define WS_XB    (WS_GW + NEXP * T_TOK * 4)
#define WS_G     (WS_XB + T_TOK * HDIM * 2)
// g: 4096 pairs x IDIM bf16 = 29,360,128 B ; total ~33.7 MB

typedef __attribute__((ext_vector_type(8))) short bf16x8;
typedef __attribute__((ext_vector_type(16))) float f32x16;

__device__ __forceinline__ unsigned short f2bf(float f) {
    union { float f; unsigned int u; } a; a.f = f;
    unsigned int u = a.u;
    return (unsigned short)((u + 0x7fffu + ((u >> 16) & 1u)) >> 16);
}

// packed fp32->bf16 RNE, 2 elems / instr
__device__ __forceinline__ unsigned int cvt_pk_bf16(float lo, float hi) {
    unsigned int r;
    asm("v_cvt_pk_bf16_f32 %0, %1, %2" : "=v"(r) : "v"(lo), "v"(hi));
    return r;
}

__device__ __forceinline__ uint4 pack8(const float4 a, const float4 b) {
    uint4 r;
    r.x = cvt_pk_bf16(a.x, a.y);
    r.y = cvt_pk_bf16(a.z, a.w);
    r.z = cvt_pk_bf16(b.x, b.y);
    r.w = cvt_pk_bf16(b.z, b.w);
    return r;
}

// async global->LDS, 16B per lane; dest = wave-uniform base + lane*16
__device__ __forceinline__ void gload16(const void* gsrc, void* ldst) {
    __builtin_amdgcn_global_load_lds(
        (const __attribute__((address_space(1))) unsigned int*)gsrc,
        (__attribute__((address_space(3))) unsigned int*)ldst, 16, 0, 0);
}

__global__ __launch_bounds__(256) void xcvt_kernel(
    const float* __restrict__ x, unsigned short* __restrict__ xb)
{
    int i = (blockIdx.x * 256 + threadIdx.x) * 8;
    float4 a = *(const float4*)(x + i);
    float4 b = *(const float4*)(x + i + 4);
    *(uint4*)(xb + i) = pack8(a, b);
}

__global__ __launch_bounds__(256) void router_kernel(
    const float* __restrict__ x, const float* __restrict__ gate_w,
    int* __restrict__ cnt, int* __restrict__ tok, float* __restrict__ gw)
{
    int t = blockIdx.x * 4 + (threadIdx.x >> 6);
    int lane = threadIdx.x & 63;
    if (t >= T_TOK) return;
    const float* xr = x + (size_t)t * HDIM;
    float part[NEXP];
#pragma unroll
    for (int e = 0; e < NEXP; e++) part[e] = 0.f;
    for (int h = lane; h < HDIM; h += 64) {
        float xv = xr[h];
#pragma unroll
        for (int e = 0; e < NEXP; e++) part[e] += xv * gate_w[e * HDIM + h];
    }
#pragma unroll
    for (int e = 0; e < NEXP; e++) {
        float v = part[e];
#pragma unroll
        for (int o = 32; o > 0; o >>= 1) v += __shfl_xor(v, o);
        part[e] = v;
    }
    if (lane == 0) {
        int i0 = 0; float v0 = part[0];
#pragma unroll
        for (int e = 1; e < NEXP; e++) if (part[e] > v0) { v0 = part[e]; i0 = e; }
        int i1 = -1; float v1 = -3.4e38f;
#pragma unroll
        for (int e = 0; e < NEXP; e++) if (e != i0 && part[e] > v1) { v1 = part[e]; i1 = e; }
        float d = __expf(v1 - v0);
        float w1v = d / (1.f + d);
        float w0v = 1.f - w1v;
        int p0 = atomicAdd(&cnt[i0], 1);
        tok[i0 * T_TOK + p0] = t; gw[i0 * T_TOK + p0] = w0v;
        int p1 = atomicAdd(&cnt[i1], 1);
        tok[i1 * T_TOK + p1] = t; gw[i1 * T_TOK + p1] = w1v;
    }
}

__global__ void scan_kernel(const int* __restrict__ cnt, int* __restrict__ base,
                            int* __restrict__ tileE, int* __restrict__ tileM,
                            int* __restrict__ ntot)
{
    if (threadIdx.x == 0) {
        int s = 0, nt = 0;
        for (int e = 0; e < NEXP; e++) {
            base[e] = s; s += cnt[e];
            for (int m0 = 0; m0 < cnt[e]; m0 += 128) {
                tileE[nt] = e; tileM[nt] = m0; nt++;
            }
        }
        *ntot = nt;
    }
}

// ffn1: g = silu(x@w1^T) * (x@w3^T). Tile 128 tok x 64 i, BK=64, 4 waves,
// xs double-buffered via global_load_lds (pre-swizzled source), weights
// reg-staged fp32->bf16. LDS 48 KB -> 3 blocks/CU.
__global__ __launch_bounds__(256, 3) void ffn1_mfma(
    const unsigned short* __restrict__ xb,
    const float* __restrict__ w1,
    const float* __restrict__ w3,
    const int* __restrict__ cnt, const int* __restrict__ base,
    const int* __restrict__ tok,
    const int* __restrict__ tileE, const int* __restrict__ tileM,
    const int* __restrict__ ntot,
    unsigned short* __restrict__ g)
{
    const int ti = blockIdx.y;
    if (ti >= *ntot) return;
    const int e = tileE[ti];
    const int m0 = tileM[ti];
    const int cntE = cnt[e];
    const int i0 = blockIdx.x * 64;
    const int tid = threadIdx.x;
    const int lane = tid & 63;
    const int wid = tid >> 6;

    __shared__ __align__(16) unsigned char lds[49152];
    // xs[0] @0 (16K), xs[1] @16384 (16K), w1s @32768 (8K), w3s @40960 (8K)

    // ---- x gather sources for global_load_lds (swizzle folded into source)
    const int xrr = (lane >> 3);                 // 0..7 row-in-instr
    const unsigned xoff = ((((unsigned)(lane & 7)) * 16) ^ (((unsigned)xrr) << 4)) >> 1;
    const unsigned short* xsrc[4];
#pragma unroll
    for (int i = 0; i < 4; i++) {
        int row = wid * 32 + i * 8 + xrr;
        int t = tok[e * T_TOK + min(m0 + row, cntE - 1)];
        xsrc[i] = xb + (size_t)t * HDIM + xoff;
    }

    // ---- weight staging (reg -> cvt -> LDS)
    const int rw = tid >> 2;                     // 0..63 (i-row)
    const int kq = tid & 3;                      // 16-float chunk
    const unsigned swzW = ((unsigned)(rw & 7)) << 4;
    const unsigned wd0 = (((unsigned)kq) * 32) ^ swzW;
    const unsigned wd1 = (((unsigned)kq) * 32 + 16) ^ swzW;
    const float* w1e = w1 + ((size_t)e * IDIM + i0 + rw) * HDIM + kq * 16;
    const float* w3e = w3 + ((size_t)e * IDIM + i0 + rw) * HDIM + kq * 16;

    f32x16 acc1[2], acc3[2];
#pragma unroll
    for (int a = 0; a < 2; a++)
#pragma unroll
        for (int r = 0; r < 16; r++) { acc1[a][r] = 0.f; acc3[a][r] = 0.f; }

    const int wr = wid >> 1;                     // token half (0/1)
    const int wc = wid & 1;                      // i half (0/1) -> 32 cols
    const unsigned lrow = (unsigned)(lane & 31);
    const unsigned lswz = (lrow & 7) << 4;
    const unsigned hi16 = (unsigned)((lane >> 5) * 16);
    const unsigned aRow = (wr * 64 + lrow) * 128;
    const unsigned bRow1 = 32768u + (wc * 32 + lrow) * 128;
    const unsigned bRow3 = 40960u + (wc * 32 + lrow) * 128;

    float4 wva[4], wvb[4];

    // prologue: k=0 loads
#pragma unroll
    for (int i = 0; i < 4; i++)
        gload16(xsrc[i], lds + (wid * 32 + i * 8) * 128);
#pragma unroll
    for (int i = 0; i < 4; i++) {
        wva[i] = *(const float4*)(w1e + i * 4);
        wvb[i] = *(const float4*)(w3e + i * 4);
    }

    for (int st = 0; st < HDIM / 64; st++) {
        const unsigned xsb = (unsigned)(st & 1) * 16384u;
        const int k0 = st * 64;
        __syncthreads();   // xs[cur] landed (vmcnt drain); prev weight reads done
        *(uint4*)(lds + 32768u + rw * 128 + wd0) = pack8(wva[0], wva[1]);
        *(uint4*)(lds + 32768u + rw * 128 + wd1) = pack8(wva[2], wva[3]);
        *(uint4*)(lds + 40960u + rw * 128 + wd0) = pack8(wvb[0], wvb[1]);
        *(uint4*)(lds + 40960u + rw * 128 + wd1) = pack8(wvb[2], wvb[3]);
        __syncthreads();   // weight writes visible

        // issue NEXT K-step's loads — they fly under the MFMAs + next barrier
        if (k0 + 64 < HDIM) {
            const unsigned xnb = xsb ^ 16384u;
#pragma unroll
            for (int i = 0; i < 4; i++)
                gload16(xsrc[i] + k0 + 64, lds + xnb + (wid * 32 + i * 8) * 128);
#pragma unroll
            for (int i = 0; i < 4; i++) {
                wva[i] = *(const float4*)(w1e + k0 + 64 + i * 4);
                wvb[i] = *(const float4*)(w3e + k0 + 64 + i * 4);
            }
        }

#pragma unroll
        for (int s = 0; s < 4; s++) {
            const unsigned off = (((unsigned)(s * 32)) + hi16) ^ lswz;
            bf16x8 a0 = *(const bf16x8*)(lds + xsb + aRow + off);
            bf16x8 a1 = *(const bf16x8*)(lds + xsb + aRow + 32 * 128 + off);
            bf16x8 b1 = *(const bf16x8*)(lds + bRow1 + off);
            bf16x8 b3 = *(const bf16x8*)(lds + bRow3 + off);
            acc1[0] = __builtin_amdgcn_mfma_f32_32x32x16_bf16(a0, b1, acc1[0], 0, 0, 0);
            acc1[1] = __builtin_amdgcn_mfma_f32_32x32x16_bf16(a1, b1, acc1[1], 0, 0, 0);
            acc3[0] = __builtin_amdgcn_mfma_f32_32x32x16_bf16(a0, b3, acc3[0], 0, 0, 0);
            acc3[1] = __builtin_amdgcn_mfma_f32_32x32x16_bf16(a1, b3, acc3[1], 0, 0, 0);
        }
    }

    const int pbase = base[e] + m0;
    const int colI = i0 + wc * 32 + (int)lrow;
    const int rb4 = 4 * (lane >> 5);
#pragma unroll
    for (int ma = 0; ma < 2; ma++) {
#pragma unroll
        for (int r = 0; r < 16; r++) {
            int row = (r & 3) + 8 * (r >> 2) + rb4;
            int m = wr * 64 + ma * 32 + row;
            if (m0 + m < cntE) {
                float h1 = acc1[ma][r], h3 = acc3[ma][r];
                float v = (h1 / (1.f + __expf(-h1))) * h3;
                g[(size_t)(pbase + m) * IDIM + colI] = f2bf(v);
            }
        }
    }
}

// ffn2: out[t,h] += gate * (g @ w2^T). Tile 128 pairs x 64 h, split-K x4,
// gs double-buffered via global_load_lds. LDS 40 KB -> 4 blocks/CU.
__global__ __launch_bounds__(256, 4) void ffn2_mfma(
    const unsigned short* __restrict__ g,
    const float* __restrict__ w2,
    const int* __restrict__ cnt, const int* __restrict__ base,
    const int* __restrict__ tok, const float* __restrict__ gw,
    const int* __restrict__ tileE, const int* __restrict__ tileM,
    const int* __restrict__ ntot,
    float* __restrict__ out)
{
    const int ti = blockIdx.y;
    if (ti >= *ntot) return;
    const int e = tileE[ti];
    const int m0 = tileM[ti];
    const int cntE = cnt[e];
    const int pane = blockIdx.x;               // 0..63
    const int h0 = (pane & 15) * 64;
    const int ks = pane >> 4;                  // 0..3
    const int tid = threadIdx.x;
    const int lane = tid & 63;
    const int wid = tid >> 6;

    __shared__ __align__(16) unsigned char lds[40960];
    // gs[0] @0 (16K), gs[1] @16384 (16K), w2s @32768 (8K)

    const int kbeg = ks * (IDIM / 4);          // 896-elem split, 14 K-steps

    const int xrr = (lane >> 3);
    const unsigned xoff = ((((unsigned)(lane & 7)) * 16) ^ (((unsigned)xrr) << 4)) >> 1;
    const unsigned short* gsrc[4];
    const int be = base[e];
#pragma unroll
    for (int i = 0; i < 4; i++) {
        int row = wid * 32 + i * 8 + xrr;
        int grow = be + min(m0 + row, cntE - 1);
        gsrc[i] = g + (size_t)grow * IDIM + kbeg + xoff;
    }

    const int rw = tid >> 2;                   // 0..63 (h-row)
    const int kq = tid & 3;
    const unsigned swzW = ((unsigned)(rw & 7)) << 4;
    const unsigned wd0 = (((unsigned)kq) * 32) ^ swzW;
    const unsigned wd1 = (((unsigned)kq) * 32 + 16) ^ swzW;
    const float* w2e = w2 + ((size_t)e * HDIM + h0 + rw) * IDIM + kbeg + kq * 16;

    f32x16 acc[2];
#pragma unroll
    for (int a = 0; a < 2; a++)
#pragma unroll
        for (int r = 0; r < 16; r++) acc[a][r] = 0.f;

    const int wr = wid >> 1;
    const int wc = wid & 1;
    const unsigned lrow = (unsigned)(lane & 31);
    const unsigned lswz = (lrow & 7) << 4;
    const unsigned hi16 = (unsigned)((lane >> 5) * 16);
    const unsigned aRow = (wr * 64 + lrow) * 128;
    const unsigned bRow = 32768u + (wc * 32 + lrow) * 128;

    float4 wv[4];
#pragma unroll
    for (int i = 0; i < 4; i++)
        gload16(gsrc[i], lds + (wid * 32 + i * 8) * 128);
#pragma unroll
    for (int i = 0; i < 4; i++)
        wv[i] = *(const float4*)(w2e + i * 4);

    const int NST = (IDIM / 4) / 64;           // 14
    for (int st = 0; st < NST; st++) {
        const unsigned xsb = (unsigned)(st & 1) * 16384u;
        const int k0 = st * 64;
        __syncthreads();
        *(uint4*)(lds + 32768u + rw * 128 + wd0) = pack8(wv[0], wv[1]);
        *(uint4*)(lds + 32768u + rw * 128 + wd1) = pack8(wv[2], wv[3]);
        __syncthreads();

        if (st + 1 < NST) {
            const unsigned xnb = xsb ^ 16384u;
#pragma unroll
            for (int i = 0; i < 4; i++)
                gload16(gsrc[i] + k0 + 64, lds + xnb + (wid * 32 + i * 8) * 128);
#pragma unroll
            for (int i = 0; i < 4; i++)
                wv[i] = *(const float4*)(w2e + k0 + 64 + i * 4);
        }

#pragma unroll
        for (int s = 0; s < 4; s++) {
            const unsigned off = (((unsigned)(s * 32)) + hi16) ^ lswz;
            bf16x8 a0 = *(const bf16x8*)(lds + xsb + aRow + off);
            bf16x8 a1 = *(const bf16x8*)(lds + xsb + aRow + 32 * 128 + off);
            bf16x8 b0 = *(const bf16x8*)(lds + bRow + off);
            acc[0] = __builtin_amdgcn_mfma_f32_32x32x16_bf16(a0, b0, acc[0], 0, 0, 0);
            acc[1] = __builtin_amdgcn_mfma_f32_32x32x16_bf16(a1, b0, acc[1], 0, 0, 0);
        }
    }

    const int rb4 = 4 * (lane >> 5);
    const int hcol = h0 + wc * 32 + (int)lrow;
#pragma unroll
    for (int ma = 0; ma < 2; ma++) {
#pragma unroll
        for (int r = 0; r < 16; r++) {
            int row = (r & 3) + 8 * (r >> 2) + rb4;
            int m = wr * 64 + ma * 32 + row;
            if (m0 + m < cntE) {
                int idx = e * T_TOK + m0 + m;
                int t = tok[idx];
                float wgt = gw[idx];
                atomicAdd(out + (size_t)t * HDIM + hcol, wgt * acc[ma][r]);
            }
        }
    }
}

extern "C" void kernel_launch(void* const* d_in, const int* in_sizes, int n_in,
                              void* d_out, int out_size, void* d_ws, size_t ws_size,
                              hipStream_t stream) {
    const float* x      = (const float*)d_in[0];
    const float* gate_w = (const float*)d_in[1];
    const float* w1     = (const float*)d_in[2];
    const float* w2     = (const float*)d_in[3];
    const float* w3     = (const float*)d_in[4];
    float* out = (float*)d_out;
    char* ws = (char*)d_ws;
    int* cnt   = (int*)(ws + WS_CNT);
    int* base  = (int*)(ws + WS_BASE);
    int* tileE = (int*)(ws + WS_TE);
    int* tileM = (int*)(ws + WS_TM);
    int* ntot  = (int*)(ws + WS_NT);
    int* tok   = (int*)(ws + WS_TOK);
    float* gw  = (float*)(ws + WS_GW);
    unsigned short* xb = (unsigned short*)(ws + WS_XB);
    unsigned short* g  = (unsigned short*)(ws + WS_G);

    hipMemsetAsync(cnt, 0, 64, stream);
    hipMemsetAsync(d_out, 0, (size_t)out_size * sizeof(float), stream);

    xcvt_kernel<<<T_TOK * HDIM / (256 * 8), 256, 0, stream>>>(x, xb);
    router_kernel<<<T_TOK / 4, 256, 0, stream>>>(x, gate_w, cnt, tok, gw);
    scan_kernel<<<1, 64, 0, stream>>>(cnt, base, tileE, tileM, ntot);
    ffn1_mfma<<<dim3(IDIM / 64, MAXTILE), 256, 0, stream>>>(xb, w1, w3, cnt, base, tok, tileE, tileM, ntot, g);
    ffn2_mfma<<<dim3(64, MAXTILE), 256, 0, stream>>>(g, w2, cnt, base, tok, gw, tileE, tileM, ntot, out);
}